// Round 3
// baseline (328.935 us; speedup 1.0000x reference)
//
#include <hip/hip_runtime.h>

// SparseWeights: y = x @ (W_dense + scatter(sparse))^T + bias
// Round 3: 256x256 tile, BK=32, 4-deep LDS ring, fragment-level software
// pipelining: A-frags double-buffered in registers, prefetched during the
// previous tile's MFMA cluster with counted lgkmcnt(8). 2 barriers/K-tile.

typedef __attribute__((ext_vector_type(8))) __bf16 bf16x8;
typedef __attribute__((ext_vector_type(4))) float f32x4;
typedef __attribute__((ext_vector_type(8))) unsigned short u16x8;

#define BARRIER()   asm volatile("s_barrier" ::: "memory")
#define WAITLGKM(n) asm volatile("s_waitcnt lgkmcnt(" #n ")" ::: "memory")
#define WAITVM(n)   asm volatile("s_waitcnt vmcnt(" #n ")" ::: "memory")
#define SCHED0()    __builtin_amdgcn_sched_barrier(0)

__device__ __forceinline__ unsigned short f2bf(float f) {
  unsigned int u = __builtin_bit_cast(unsigned int, f);
  u += 0x7FFFu + ((u >> 16) & 1u);   // round-to-nearest-even
  return (unsigned short)(u >> 16);
}

// ---- prepass 1/3: f32 -> bf16 bulk convert (vectorized x8) ----
__global__ __launch_bounds__(256) void cvt_f32_bf16(
    const float* __restrict__ s, unsigned short* __restrict__ d, long n8) {
  long i = (long)blockIdx.x * blockDim.x + threadIdx.x;
  const long stride = (long)gridDim.x * blockDim.x;
  for (; i < n8; i += stride) {
    const float4* sp = (const float4*)(s + i * 8);
    float4 a = sp[0];
    float4 b = sp[1];
    u16x8 o;
    o[0] = f2bf(a.x); o[1] = f2bf(a.y); o[2] = f2bf(a.z); o[3] = f2bf(a.w);
    o[4] = f2bf(b.x); o[5] = f2bf(b.y); o[6] = f2bf(b.z); o[7] = f2bf(b.w);
    *(u16x8*)(d + i * 8) = o;
  }
}

// ---- prepass 2/3: scatter sparse values into bf16 W ----
__global__ __launch_bounds__(256) void sparse_scatter(
    const float* __restrict__ dense, const float* __restrict__ vals,
    const int* __restrict__ rows, const int* __restrict__ cols,
    unsigned short* __restrict__ Wb, int nnz, int K) {
  int i = blockIdx.x * blockDim.x + threadIdx.x;
  if (i < nnz) {
    size_t off = (size_t)rows[i] * (size_t)K + (size_t)cols[i];
    Wb[off] = f2bf(dense[off] + vals[i]);
  }
}

// =====================================================================
// 256x256 GEMM, 512 threads = 8 waves (2Mx4N), wave tile 128x64 =
// acc[8][4] of 16x16x32 frags. BK=32, LDS ring of 4 K-tiles (128 KiB).
// Register pipeline: A-frags double-buffered (aA/aB), prefetched one
// K-tile ahead, awaited with lgkmcnt(8); B-frags read in-phase (first
// in LDS queue). Stage distance 3, counted vmcnt(8). Per K-tile:
//   BARRIER; STAGE(t+3); vmcnt(8); BARRIER;
//   read b(t); prefetch A(t+1); lgkmcnt(8); 32 MFMA (setprio 1).
// Hazards: ring overwritten at iter t held tile t-1, whose last readers
// confirmed completion via their own counted lgkm wait at iter t-1;
// the iter-t leading barrier conveys that to the staging waves.
// =====================================================================
__global__ __launch_bounds__(512, 2) void gemm256(
    const unsigned short* __restrict__ A,   // [Tm][K] bf16
    const unsigned short* __restrict__ B,   // [Mn][K] bf16
    const float* __restrict__ bias,
    float* __restrict__ C,
    int Tm, int Mn, int K) {
  extern __shared__ __align__(16) char smem[];   // 4 rings * 32768 B

  const int tid  = threadIdx.x;
  const int lane = tid & 63;
  const int wid  = tid >> 6;
  const int wm = (wid >> 2) * 128;
  const int wn = (wid & 3) * 64;

  // T1: XCD-aware bijective swizzle (nwg = 512, % 8 == 0)
  const int nwg = gridDim.x;
  int bid = blockIdx.x;
  if ((nwg & 7) == 0) bid = (bid & 7) * (nwg >> 3) + (bid >> 3);
  const int ntn = Mn >> 8;
  const int bm0 = (bid / ntn) << 8;
  const int bn0 = (bid % ntn) << 8;

  const int NT = K >> 5;             // K-tiles of 32

  // Staging: thread t loads 16 B to LDS byte t*16 (linear dest);
  // source 16B-quad pre-swizzled: quad q at row r holds global quad
  // q ^ ((r>>1)&3)  (rule #21: swizzle source + read, keep dest linear).
  const int srow  = tid >> 2;
  const int squad = (tid & 3) ^ ((tid >> 3) & 3);
  const unsigned short* Asrc = A + (size_t)(bm0 + srow) * K + squad * 8;
  const unsigned short* Bsrc = B + (size_t)(bn0 + srow) * K + squad * 8;
  const size_t rstep = (size_t)128 * K;
  const int ldst = tid * 16;

#define STAGE(SRC, RING_OFF, KOFF) do {                                          \
    __builtin_amdgcn_global_load_lds(                                            \
        (const __attribute__((address_space(1))) void*)((SRC) + (KOFF)),         \
        (__attribute__((address_space(3))) void*)(smem + (RING_OFF) + ldst),     \
        16, 0, 0);                                                               \
    __builtin_amdgcn_global_load_lds(                                            \
        (const __attribute__((address_space(1))) void*)((SRC) + rstep + (KOFF)), \
        (__attribute__((address_space(3))) void*)(smem + (RING_OFF) + 8192 + ldst), \
        16, 0, 0);                                                               \
  } while (0)

  // Read-side swizzled offsets: frag row = base + fr, byte =
  // row*64 + ((cq ^ ((fr>>1)&3))<<4).
  const int fr = lane & 15, cq = lane >> 4;
  const int roff = ((cq ^ ((fr >> 1) & 3)) << 4);
  const int aoff = (wm + fr) * 64 + roff;
  const int boff = (wn + fr) * 64 + roff;

  f32x4 acc[8][4] = {};
  bf16x8 aA[8], aB[8], b[4];

  // ---- prologue: stage tiles 0,1,2; read A(0) into aA ----
  STAGE(Asrc, 0, 0);              STAGE(Bsrc, 16384, 0);
  STAGE(Asrc, 32768, 32);         STAGE(Bsrc, 32768 + 16384, 32);
  STAGE(Asrc, 65536, 64);         STAGE(Bsrc, 65536 + 16384, 64);
  WAITVM(8);                      // tile 0 landed (own loads)
  BARRIER();                      // everyone's tile 0 landed
#pragma unroll
  for (int m = 0; m < 8; ++m)
    aA[m] = *(const bf16x8*)(smem + aoff + m * 1024);

  // ---- main loop, unrolled x2 for static frag-buffer names ----
#define BODY(T, CUR, NXT) do {                                                   \
    const int t_ = (T);                                                          \
    BARRIER();   /* conveys prior iteration's read confirmations */              \
    const int so_ = ((t_ + 3) & 3) * 32768;                                      \
    if (t_ + 3 < NT) {                                                           \
      const int ks_ = (t_ + 3) * 32;                                             \
      STAGE(Asrc, so_, ks_);                                                     \
      STAGE(Bsrc, so_ + 16384, ks_);                                             \
      WAITVM(8);          /* tile t+1 landed; 8 loads stay in flight */          \
    } else if (t_ + 2 < NT) { WAITVM(4); }                                       \
    else if (t_ + 1 < NT)   { WAITVM(0); }                                       \
    BARRIER();   /* ring (t+1)&3 valid for all waves */                          \
    {                                                                            \
      const char* Br_ = smem + (t_ & 3) * 32768 + 16384;                         \
      _Pragma("unroll")                                                          \
      for (int n = 0; n < 4; ++n)                                                \
        b[n] = *(const bf16x8*)(Br_ + boff + n * 1024);                          \
    }                                                                            \
    SCHED0();    /* pin issue order: b reads precede A-prefetch */               \
    if (t_ + 1 < NT) {                                                           \
      const char* An_ = smem + ((t_ + 1) & 3) * 32768;                           \
      _Pragma("unroll")                                                          \
      for (int m = 0; m < 8; ++m)                                                \
        NXT[m] = *(const bf16x8*)(An_ + aoff + m * 1024);                        \
      WAITLGKM(8);  /* CUR + b done; 8 prefetch reads stay in flight */          \
    } else {                                                                     \
      WAITLGKM(0);                                                               \
    }                                                                            \
    SCHED0();                                                                    \
    __builtin_amdgcn_s_setprio(1);                                               \
    _Pragma("unroll")                                                            \
    for (int m = 0; m < 8; ++m)                                                  \
      _Pragma("unroll")                                                          \
      for (int n = 0; n < 4; ++n)                                                \
        acc[m][n] = __builtin_amdgcn_mfma_f32_16x16x32_bf16(CUR[m], b[n],        \
                                                            acc[m][n], 0, 0, 0);\
    __builtin_amdgcn_s_setprio(0);                                               \
  } while (0)

  for (int t = 0; t < NT; t += 2) {
    BODY(t,     aA, aB);
    BODY(t + 1, aB, aA);
  }
#undef BODY
#undef STAGE

  // ---- epilogue: C/D layout col = lane&15, row = (lane>>4)*4 + q ----
  const int c4 = cq * 4;
#pragma unroll
  for (int n = 0; n < 4; ++n) {
    const int col = bn0 + wn + n * 16 + fr;
    const float bv = bias[col];
#pragma unroll
    for (int m = 0; m < 8; ++m) {
      const size_t rowb = (size_t)(bm0 + wm + m * 16 + c4);
#pragma unroll
      for (int q = 0; q < 4; ++q)
        C[(rowb + q) * (size_t)Mn + col] = acc[m][n][q] + bv;
    }
  }
}

extern "C" void kernel_launch(void* const* d_in, const int* in_sizes, int n_in,
                              void* d_out, int out_size, void* d_ws, size_t ws_size,
                              hipStream_t stream) {
  const float* x     = (const float*)d_in[0];
  const float* dw    = (const float*)d_in[1];
  const float* bias  = (const float*)d_in[2];
  const float* sv    = (const float*)d_in[3];
  const int*   rows  = (const int*)d_in[4];
  const int*   cols  = (const int*)d_in[5];
  float* out = (float*)d_out;

  const int  Mn = in_sizes[2];                       // 4096
  const long wElems = (long)in_sizes[1];             // M*K
  const int  K  = (int)(wElems / Mn);                // 4096
  const long xElems = (long)in_sizes[0];             // T*K
  const int  Tm = (int)(xElems / K);                 // 8192
  const int  nnz = in_sizes[3];

  unsigned short* Wb = (unsigned short*)d_ws;        // [M*K] bf16
  unsigned short* Xb = Wb + wElems;                  // [T*K] bf16

  cvt_f32_bf16<<<2048, 256, 0, stream>>>(dw, Wb, wElems / 8);
  sparse_scatter<<<(nnz + 255) / 256, 256, 0, stream>>>(dw, sv, rows, cols, Wb, nnz, K);
  cvt_f32_bf16<<<2048, 256, 0, stream>>>(x, Xb, xElems / 8);

  dim3 grid((Tm >> 8) * (Mn >> 8));                  // 32*16 = 512
  gemm256<<<grid, 512, 131072, stream>>>(Xb, Wb, bias, out, Tm, Mn, K);
}